// Round 23
// baseline (579.144 us; speedup 1.0000x reference)
//
#include <hip/hip_runtime.h>

#define N 4096
#define D 10000
#define D4 2500          // D/4
#define C 10
#define NB 16            // number of 256-step blocks
#define B 256            // steps per block
#define CWG 1024         // corrector WGs (static 4-row ownership over all N)
#define ROWS 4           // rows per corrector WG
#define RWG (CWG + 1)    // retrain grid size
#define BAND 4           // rolling band (6 measured worse in R22; revert)

// ---- workspace layout (float offsets) ----
#define AM_OFF    0                            // [C*D] (pad 100096) -- am0
#define SFIN_OFF  100096                       // [N*C] corrected scores
#define HV2_OFF   (SFIN_OFF + N*C)             // [N]
#define AN_OFF    (HV2_OFF + N)                // [16] initial ||am_c||^2
#define ANF_OFF   (AN_OFF + 16)                // [16] final   ||am_c||^2
#define WLIST_OFF (ANF_OFF + 16)               // [N] packed gidx|pred<<12|lab<<16
#define WCUM_OFF  (WLIST_OFF + N)              // [32] ints
#define SLOTS_OFF (WCUM_OFF + 32)              // [RWG*32] ints, phase-1 done slots
#define FLAGR_OFF (SLOTS_OFF + RWG*32)         // [8*64] ints: per-XCD flag replicas
#define MIST_OFF  (FLAGR_OFF + 8*64)           // [8]
#define REQ_OFF   (MIST_OFF + 8)               // [8] int: (reqId<<12)|(k<<8)|jstar
#define RSLOT_OFF (REQ_OFF + 8)                // [CWG*8] ints: per-owner response slots
#define GROW_OFF  (RSLOT_OFF + CWG*8)          // [B] floats: on-demand G row

// ---------------- build_am: segment-sum, float4, register accumulate + atomics ------------
__global__ __launch_bounds__(256) void build_am_kernel(float* __restrict__ am,
        const float* __restrict__ X, const int* __restrict__ labels){
    int d4 = blockIdx.x*256 + threadIdx.x;
    if (d4 >= D4) return;
    int i0 = blockIdx.y * (N/32);
    const float4* X4 = (const float4*)X;
    float4 acc[C];
    #pragma unroll
    for (int c=0;c<C;c++) acc[c] = make_float4(0.f,0.f,0.f,0.f);
    for (int i=i0; i<i0+(N/32); ++i){
        int lab = labels[i];
        float4 x = X4[(size_t)i*D4 + d4];
        #pragma unroll
        for (int c=0;c<C;c++){
            float m = (lab==c) ? 1.f : 0.f;
            acc[c].x += m*x.x; acc[c].y += m*x.y; acc[c].z += m*x.z; acc[c].w += m*x.w;
        }
    }
    #pragma unroll
    for (int c=0;c<C;c++){
        float* p = &am[(size_t)c*D + d4*4];
        atomicAdd(p+0, acc[c].x); atomicAdd(p+1, acc[c].y);
        atomicAdd(p+2, acc[c].z); atomicAdd(p+3, acc[c].w);
    }
}

// ---------------- row sum-of-squares of am -> out[c] ----------------
__global__ __launch_bounds__(256) void rownorm2_kernel(const float* __restrict__ am,
        float* __restrict__ out){
    int c = blockIdx.x, t = threadIdx.x;
    const float4* a4 = (const float4*)(am + (size_t)c*D);
    float p = 0.f;
    for (int d=t; d<D4; d+=256){ float4 v = a4[d]; p += v.x*v.x+v.y*v.y+v.z*v.z+v.w*v.w; }
    #pragma unroll
    for (int off=32; off>=1; off>>=1) p += __shfl_down(p, off);
    __shared__ float wsum[4];
    int wid = t>>6, lane = t&63;
    if (lane==0) wsum[wid]=p;
    __syncthreads();
    if (t==0) out[c] = wsum[0]+wsum[1]+wsum[2]+wsum[3];
}

// ---- corrector chunk: 4 wrongs per d-pass ------------------------------------------------
#define CORR_PASS(wBeg, wEnd) \
    for (int w = (wBeg); w < (wEnd); w += 4){ \
        int n = (wEnd) - w; \
        int pk0 = wrongList[w]; \
        int pk1 = wrongList[(n>1)? w+1 : w]; \
        int pk2 = wrongList[(n>2)? w+2 : w]; \
        int pk3 = wrongList[(n>3)? w+3 : w]; \
        float e1=(n>1)?1.f:0.f, e2=(n>2)?1.f:0.f, e3=(n>3)?1.f:0.f; \
        const float4 *xw0 = X4+(size_t)(pk0&4095)*D4, *xw1 = X4+(size_t)(pk1&4095)*D4; \
        const float4 *xw2 = X4+(size_t)(pk2&4095)*D4, *xw3 = X4+(size_t)(pk3&4095)*D4; \
        float gg0[ROWS], gg1[ROWS], gg2[ROWS], gg3[ROWS]; \
        _Pragma("unroll") for (int r=0;r<ROWS;r++){ gg0[r]=0.f;gg1[r]=0.f;gg2[r]=0.f;gg3[r]=0.f; } \
        for (int d=t; d<D4; d+=256){ \
            float4 x0=xw0[d], x1=xw1[d], x2=xw2[d], x3=xw3[d]; \
            _Pragma("unroll") for (int r=0;r<ROWS;r++){ \
                float4 a = X4[(size_t)(R0+r)*D4 + d]; \
                gg0[r]+=a.x*x0.x+a.y*x0.y+a.z*x0.z+a.w*x0.w; \
                gg1[r]+=a.x*x1.x+a.y*x1.y+a.z*x1.z+a.w*x1.w; \
                gg2[r]+=a.x*x2.x+a.y*x2.y+a.z*x2.z+a.w*x2.w; \
                gg3[r]+=a.x*x3.x+a.y*x3.y+a.z*x3.z+a.w*x3.w; } \
        } \
        int p0=(pk0>>12)&15,l0=(pk0>>16)&15, p1=(pk1>>12)&15,l1=(pk1>>16)&15; \
        int p2=(pk2>>12)&15,l2=(pk2>>16)&15, p3=(pk3>>12)&15,l3=(pk3>>16)&15; \
        _Pragma("unroll") for (int c=0;c<C;c++){ \
            float c0 = ((c==l0)?1.f:0.f) - ((c==p0)?1.f:0.f); \
            float c1 = e1*(((c==l1)?1.f:0.f) - ((c==p1)?1.f:0.f)); \
            float c2 = e2*(((c==l2)?1.f:0.f) - ((c==p2)?1.f:0.f)); \
            float c3 = e3*(((c==l3)?1.f:0.f) - ((c==p3)?1.f:0.f)); \
            _Pragma("unroll") for (int r=0;r<ROWS;r++) \
                pp[r][c] += c0*gg0[r] + c1*gg1[r] + c2*gg2[r] + c3*gg3[r]; \
        } \
    }

// == retrain: WG0 = sequencer (on-demand G rows); WGs 1..1024 = correctors+row-servers =====
// flag replicated per-XCD (8 lines): readers poll flagRep[(bx&7)*64] -> ~128 readers/line
// instead of ~1000 on one line (cross-XCD invalidation storm at each release).
__global__ __launch_bounds__(256, 5) void retrain_kernel(
        const float* __restrict__ am, const float* __restrict__ X,
        const int* __restrict__ labels,
        float* __restrict__ Sfin, float* __restrict__ hv2g,
        const float* __restrict__ an0, float* __restrict__ anf,
        int* __restrict__ wrongList, int* __restrict__ Wcum,
        int* slots, int* flagRep, int* __restrict__ mist,
        int* req, int* respSlots, float* __restrict__ Grow){
    const int bx = blockIdx.x, t = threadIdx.x;
    const float4* X4 = (const float4*)X;
    __shared__ float red[ROWS][C+1][4];
    __shared__ float s0sm[ROWS][C];
    __shared__ int vvsm;

    if (bx == 0){
        // ---------------- sequencer ----------------
        float an[C], rstd[C];
        #pragma unroll
        for (int c=0;c<C;c++){ an[c]=an0[c]; rstd[c]=rsqrtf(an[c]); }
        int Wtot = 0;
        int reqId = 0;
        for (int k=0; k<NB; ++k){
            if (t < 64){
                while (__hip_atomic_load(&slots[(size_t)(1 + k*64 + t)*32],
                                         __ATOMIC_RELAXED, __HIP_MEMORY_SCOPE_AGENT) < 1)
                    __builtin_amdgcn_s_sleep(1);
            }
            __syncthreads();
            if (t==0) (void)__hip_atomic_load(&slots[32], __ATOMIC_ACQUIRE,
                                              __HIP_MEMORY_SCOPE_AGENT);
            __syncthreads();

            if (t < 64){
                const int lane = t;
                const int base = k*B;
                float s[4][C];
                float h2o[4]; int labo[4];
                #pragma unroll
                for (int q=0;q<4;q++){
                    int j = q*64 + lane;
                    #pragma unroll
                    for (int c=0;c<C;c++) s[q][c] = Sfin[(size_t)(base+j)*C + c];
                    h2o[q] = hv2g[base + j];
                    labo[q] = labels[base + j];
                }
                int pos = -1;
                while (true){
                    int pred[4];
                    #pragma unroll
                    for (int q=0;q<4;q++){
                        float best = s[q][0]*rstd[0]; int bi=0;
                        #pragma unroll
                        for (int c=1;c<C;c++){
                            float v = s[q][c]*rstd[c];
                            if (v>best){best=v;bi=c;}
                        }
                        pred[q]=bi;
                    }
                    int jstar = 256;
                    #pragma unroll
                    for (int q=0;q<4;q++){
                        unsigned long long m =
                            __ballot((pred[q]!=labo[q]) && (q*64+lane > pos));
                        if (jstar==256 && m!=0ull)
                            jstar = q*64 + (__ffsll((unsigned long long)m)-1);
                    }
                    if (jstar >= 256) break;
                    // publish on-demand G-row request EARLY (owners compute while we update)
                    int reqWord = (reqId<<12) | (k<<8) | jstar;
                    if (lane==0)
                        __hip_atomic_store(req, reqWord, __ATOMIC_RELEASE,
                                           __HIP_MEMORY_SCOPE_AGENT);
                    reqId++;
                    int qs = jstar>>6, ls = jstar&63;
                    float sqs[C];
                    #pragma unroll
                    for (int c=0;c<C;c++)
                        sqs[c] = (qs==0)? s[0][c] : (qs==1)? s[1][c]
                               : (qs==2)? s[2][c] : s[3][c];
                    int predqs = (qs==0)? pred[0] : (qs==1)? pred[1]
                               : (qs==2)? pred[2] : pred[3];
                    int labqs  = (qs==0)? labo[0] : (qs==1)? labo[1]
                               : (qs==2)? labo[2] : labo[3];
                    float h2qs = (qs==0)? h2o[0] : (qs==1)? h2o[1]
                               : (qs==2)? h2o[2] : h2o[3];
                    float brawme = sqs[0], slvme = sqs[0];
                    #pragma unroll
                    for (int c=1;c<C;c++){
                        brawme = (c==predqs)? sqs[c] : brawme;
                        slvme  = (c==labqs)?  sqs[c] : slvme;
                    }
                    float brawB = __shfl(brawme, ls);
                    float slvB  = __shfl(slvme,  ls);
                    float h2b   = __shfl(h2qs,   ls);
                    int   pkB   = __shfl(predqs | (labqs<<8), ls);
                    int biB = pkB & 255, labB = (pkB>>8) & 255;
                    if (lane==0)
                        wrongList[Wtot] = (base + jstar) | (biB<<12) | (labB<<16);
                    Wtot++;
                    float anp = an[0], anl = an[0];
                    #pragma unroll
                    for (int c=1;c<C;c++){ anp=(c==biB)?an[c]:anp; anl=(c==labB)?an[c]:anl; }
                    float anp_new = anp - 2.f*brawB + h2b;
                    float anl_new = anl + 2.f*slvB  + h2b;
                    float rp = rsqrtf(anp_new), rl = rsqrtf(anl_new);
                    #pragma unroll
                    for (int c=0;c<C;c++){
                        an[c]   = (c==biB)? anp_new : (c==labB)? anl_new : an[c];
                        rstd[c] = (c==biB)? rp      : (c==labB)? rl      : rstd[c];
                    }
                    // wait for all 64 owner responses (per-owner slots, no RMW)
                    while (__hip_atomic_load(&respSlots[(size_t)(k*64+lane)*8],
                               __ATOMIC_RELAXED, __HIP_MEMORY_SCOPE_AGENT) != reqWord){}
                    (void)__hip_atomic_load(&respSlots[(size_t)(k*64+lane)*8],
                               __ATOMIC_ACQUIRE, __HIP_MEMORY_SCOPE_AGENT);
                    float grow[4];
                    #pragma unroll
                    for (int sl=0;sl<4;sl++) grow[sl] = Grow[sl*64 + lane];
                    #pragma unroll
                    for (int c=0;c<C;c++){
                        float sg = (c==biB)? -1.f : (c==labB)? 1.f : 0.f;
                        #pragma unroll
                        for (int sl=0;sl<4;sl++) s[sl][c] += sg * grow[sl];
                    }
                    pos = jstar;
                }
            }
            __syncthreads();
            if (t==0){
                Wcum[k+1] = Wtot;
                int fv = ((k+1)<<16) | Wtot;
                #pragma unroll
                for (int x=0; x<8; ++x)
                    __hip_atomic_store(&flagRep[x*64], fv, __ATOMIC_RELEASE,
                                       __HIP_MEMORY_SCOPE_AGENT);
            }
            __syncthreads();
        }
        if (t==0){
            mist[0] = Wtot;
            #pragma unroll
            for (int c=0;c<C;c++) anf[c] = an[c];
        }
    } else {
        // ---- corrector: rows R0..R0+3 of block m; band + s0 prologue + events + service --
        const int R0 = 4*(bx-1);
        const int m  = (bx-1) >> 6;
        int* myFlag = &flagRep[(bx & 7)*64];   // own-XCD replica (heuristic: bx%8 = XCD)
        if (m > BAND){
            if (t==0){
                while ((__hip_atomic_load(myFlag, __ATOMIC_RELAXED,
                            __HIP_MEMORY_SCOPE_AGENT) >> 16) < m - BAND)
                    __builtin_amdgcn_s_sleep(8);
            }
            __syncthreads();
        }
        {   // prologue: S0 (own 4 rows vs am0) + hv2
            const float4* a4 = (const float4*)am;
            float p0[ROWS][C]; float px[ROWS];
            #pragma unroll
            for (int r=0;r<ROWS;r++){ px[r]=0.f;
                #pragma unroll
                for (int c=0;c<C;c++) p0[r][c]=0.f; }
            for (int d=t; d<D4; d+=256){
                float4 x0 = X4[(size_t)(R0+0)*D4 + d];
                float4 x1 = X4[(size_t)(R0+1)*D4 + d];
                float4 x2 = X4[(size_t)(R0+2)*D4 + d];
                float4 x3 = X4[(size_t)(R0+3)*D4 + d];
                px[0] += x0.x*x0.x + x0.y*x0.y + x0.z*x0.z + x0.w*x0.w;
                px[1] += x1.x*x1.x + x1.y*x1.y + x1.z*x1.z + x1.w*x1.w;
                px[2] += x2.x*x2.x + x2.y*x2.y + x2.z*x2.z + x2.w*x2.w;
                px[3] += x3.x*x3.x + x3.y*x3.y + x3.z*x3.z + x3.w*x3.w;
                #pragma unroll
                for (int c=0;c<C;c++){
                    float4 a = a4[(size_t)c*D4 + d];
                    p0[0][c] += x0.x*a.x + x0.y*a.y + x0.z*a.z + x0.w*a.w;
                    p0[1][c] += x1.x*a.x + x1.y*a.y + x1.z*a.z + x1.w*a.w;
                    p0[2][c] += x2.x*a.x + x2.y*a.y + x2.z*a.z + x2.w*a.w;
                    p0[3][c] += x3.x*a.x + x3.y*a.y + x3.z*a.z + x3.w*a.w;
                }
            }
            int wid=t>>6, lane=t&63;
            #pragma unroll
            for (int r=0;r<ROWS;r++){
                #pragma unroll
                for (int v=0; v<C+1; ++v){
                    float xv = (v<C)? p0[r][v] : px[r];
                    #pragma unroll
                    for (int off=32; off>=1; off>>=1) xv += __shfl_down(xv, off);
                    if (lane==0) red[r][v][wid] = xv;
                }
            }
            __syncthreads();
            if (t < ROWS*(C+1)){
                int r = t/(C+1), v = t%(C+1);
                float s = red[r][v][0]+red[r][v][1]+red[r][v][2]+red[r][v][3];
                if (v < C) s0sm[r][v] = s;
                else hv2g[R0 + r] = s;
            }
            __syncthreads();
        }
        float pp[ROWS][C];
        #pragma unroll
        for (int r=0;r<ROWS;r++)
            #pragma unroll
            for (int c=0;c<C;c++) pp[r][c]=0.f;

        int W0 = 0;
        for (int v = 1; v <= m; ){
            if (t==0){
                int f;
                while (((f = __hip_atomic_load(myFlag, __ATOMIC_RELAXED,
                                 __HIP_MEMORY_SCOPE_AGENT)) >> 16) < v)
                    __builtin_amdgcn_s_sleep(1);
                (void)__hip_atomic_load(myFlag, __ATOMIC_ACQUIRE, __HIP_MEMORY_SCOPE_AGENT);
                int fv = f >> 16;
                vvsm = (fv < m) ? fv : m;
            }
            __syncthreads();
            int vv = vvsm;
            int end = Wcum[vv];
            CORR_PASS(W0, end)
            W0 = end;
            v = vv + 1;
            __syncthreads();
        }
        if (W0 == 0){
            if (t < ROWS*C){
                int r = t / C, c = t % C;
                Sfin[(size_t)(R0 + r)*C + c] = s0sm[r][c];
            }
            __syncthreads();
        } else {
            int wid=t>>6, lane=t&63;
            #pragma unroll
            for (int r=0;r<ROWS;r++)
                #pragma unroll
                for (int c=0;c<C;c++){
                    float xv = pp[r][c];
                    #pragma unroll
                    for (int off=32; off>=1; off>>=1) xv += __shfl_down(xv, off);
                    if (lane==0) red[r][c][wid] = xv;
                }
            __syncthreads();
            if (t < ROWS*C){
                int r = t / C, c = t % C;
                float vsum = red[r][c][0]+red[r][c][1]+red[r][c][2]+red[r][c][3];
                Sfin[(size_t)(R0 + r)*C + c] = s0sm[r][c] + vsum;
            }
            __syncthreads();
        }
        if (t==0) __hip_atomic_store(&slots[(size_t)bx*32], 1, __ATOMIC_RELEASE,
                                     __HIP_MEMORY_SCOPE_AGENT);

        // ---- service loop: compute on-demand G rows for own block m until seq passes it --
        int lastReq = -1;
        while (true){
            if (t==0){
                int r;
                while (true){
                    int f = __hip_atomic_load(myFlag, __ATOMIC_RELAXED,
                                              __HIP_MEMORY_SCOPE_AGENT) >> 16;
                    if (f >= m+1){ r = -1; break; }
                    r = __hip_atomic_load(req, __ATOMIC_RELAXED, __HIP_MEMORY_SCOPE_AGENT);
                    if (r >= 0 && r != lastReq && (((r>>8)&15) == m)){
                        (void)__hip_atomic_load(req, __ATOMIC_ACQUIRE,
                                                __HIP_MEMORY_SCOPE_AGENT);
                        break;
                    }
                    __builtin_amdgcn_s_sleep(1);
                }
                vvsm = r;
            }
            __syncthreads();
            int r = vvsm;
            if (r < 0) break;
            lastReq = r;
            {
                int jstar = r & 255;
                const float4* xw = X4 + (size_t)(m*B + jstar)*D4;
                float g0=0.f,g1=0.f,g2=0.f,g3=0.f;
                for (int d=t; d<D4; d+=256){
                    float4 v = xw[d];
                    float4 a0 = X4[(size_t)(R0+0)*D4 + d];
                    float4 a1 = X4[(size_t)(R0+1)*D4 + d];
                    float4 a2 = X4[(size_t)(R0+2)*D4 + d];
                    float4 a3 = X4[(size_t)(R0+3)*D4 + d];
                    g0 += a0.x*v.x + a0.y*v.y + a0.z*v.z + a0.w*v.w;
                    g1 += a1.x*v.x + a1.y*v.y + a1.z*v.z + a1.w*v.w;
                    g2 += a2.x*v.x + a2.y*v.y + a2.z*v.z + a2.w*v.w;
                    g3 += a3.x*v.x + a3.y*v.y + a3.z*v.z + a3.w*v.w;
                }
                int wid=t>>6, lane=t&63;
                #pragma unroll
                for (int off=32; off>=1; off>>=1){
                    g0 += __shfl_down(g0, off); g1 += __shfl_down(g1, off);
                    g2 += __shfl_down(g2, off); g3 += __shfl_down(g3, off);
                }
                if (lane==0){
                    red[0][0][wid]=g0; red[1][0][wid]=g1;
                    red[2][0][wid]=g2; red[3][0][wid]=g3;
                }
                __syncthreads();
                if (t < 4){
                    float s = red[t][0][0]+red[t][0][1]+red[t][0][2]+red[t][0][3];
                    Grow[(R0 - m*B) + t] = s;
                }
                __syncthreads();
                if (t==0)
                    __hip_atomic_store(&respSlots[(size_t)(bx-1)*8], r,
                                       __ATOMIC_RELEASE, __HIP_MEMORY_SCOPE_AGENT);
                __syncthreads();
            }
        }
    }
}

// ---- apply all wrongs to am0, write am_final + mistakes DIRECTLY to out -----------------
__global__ __launch_bounds__(256) void apply_out_kernel(const float* __restrict__ am,
        const float* __restrict__ X, const int* __restrict__ wrongList,
        const int* __restrict__ Wcum, const int* __restrict__ mist, float* __restrict__ out){
    int d4 = blockIdx.x*256 + threadIdx.x;
    if (blockIdx.x==0 && threadIdx.x==0) out[(size_t)C*D + N] = (float)mist[0];
    if (d4 >= D4) return;
    int W = Wcum[NB];
    const float4* X4 = (const float4*)X;
    float4 acc[C];
    #pragma unroll
    for (int c=0;c<C;c++) acc[c] = make_float4(0.f,0.f,0.f,0.f);
    for (int w=0; w<W; ++w){
        int pk = wrongList[w];
        int gw = pk & 4095, pcl=(pk>>12)&15, lcl=(pk>>16)&15;
        float4 x = X4[(size_t)gw*D4 + d4];
        #pragma unroll
        for (int c=0;c<C;c++){
            float coef = ((c==lcl)?1.f:0.f) - ((c==pcl)?1.f:0.f);
            acc[c].x += coef*x.x; acc[c].y += coef*x.y;
            acc[c].z += coef*x.z; acc[c].w += coef*x.w;
        }
    }
    const float4* am4 = (const float4*)am;
    float4* out4 = (float4*)out;
    #pragma unroll
    for (int c=0;c<C;c++){                      // write ALL elements (out is poisoned)
        float4 v = am4[(size_t)c*D4 + d4];
        v.x += acc[c].x; v.y += acc[c].y; v.z += acc[c].z; v.w += acc[c].w;
        out4[(size_t)c*D4 + d4] = v;
    }
}

// ---------------- final predict: 4 rows/WG, float4 ----------------
__global__ __launch_bounds__(256) void predict_kernel(const float* __restrict__ am,
        const float* __restrict__ X, const float* __restrict__ anf, float* __restrict__ outPred){
    int i0 = blockIdx.x*4, t = threadIdx.x;
    const float4* a4 = (const float4*)am;
    const float4* X4 = (const float4*)X;
    float p[4][C];
    #pragma unroll
    for (int r=0;r<4;r++)
        #pragma unroll
        for (int c=0;c<C;c++) p[r][c]=0.f;
    for (int d=t; d<D4; d+=256){
        float4 x0 = X4[(size_t)(i0+0)*D4 + d];
        float4 x1 = X4[(size_t)(i0+1)*D4 + d];
        float4 x2 = X4[(size_t)(i0+2)*D4 + d];
        float4 x3 = X4[(size_t)(i0+3)*D4 + d];
        #pragma unroll
        for (int c=0;c<C;c++){
            float4 a = a4[(size_t)c*D4 + d];
            p[0][c] += x0.x*a.x + x0.y*a.y + x0.z*a.z + x0.w*a.w;
            p[1][c] += x1.x*a.x + x1.y*a.y + x1.z*a.z + x1.w*a.w;
            p[2][c] += x2.x*a.x + x2.y*a.y + x2.z*a.z + x2.w*a.w;
            p[3][c] += x3.x*a.x + x3.y*a.y + x3.z*a.z + x3.w*a.w;
        }
    }
    __shared__ float red[4][C][4];
    int wid=t>>6, lane=t&63;
    #pragma unroll
    for (int r=0;r<4;r++)
        #pragma unroll
        for (int c=0;c<C;c++){
            float x = p[r][c];
            #pragma unroll
            for (int off=32; off>=1; off>>=1) x += __shfl_down(x, off);
            if (lane==0) red[r][c][wid] = x;
        }
    __syncthreads();
    if (t < 4){
        float best = -3.4e38f; int bi = 0;
        #pragma unroll
        for (int c=0;c<C;c++){
            float dot = red[t][c][0]+red[t][c][1]+red[t][c][2]+red[t][c][3];
            float v = dot * rsqrtf(anf[c]);
            if (v > best){ best = v; bi = c; }
        }
        outPred[i0 + t] = (float)bi;
    }
}

extern "C" void kernel_launch(void* const* d_in, const int* in_sizes, int n_in,
                              void* d_out, int out_size, void* d_ws, size_t ws_size,
                              hipStream_t stream){
    const float* X      = (const float*)d_in[0];
    const int*   labels = (const int*)d_in[1];
    float* ws   = (float*)d_ws;
    float* am   = ws + AM_OFF;
    float* Sfin = ws + SFIN_OFF;
    float* hv2  = ws + HV2_OFF;
    float* an   = ws + AN_OFF;
    float* anf  = ws + ANF_OFF;
    int*   wlist = (int*)(ws + WLIST_OFF);
    int*   wcum  = (int*)(ws + WCUM_OFF);
    int*   slots = (int*)(ws + SLOTS_OFF);
    int*   flagR = (int*)(ws + FLAGR_OFF);
    int*   mist  = (int*)(ws + MIST_OFF);
    int*   req   = (int*)(ws + REQ_OFF);
    int*   rslot = (int*)(ws + RSLOT_OFF);
    float* grow  = ws + GROW_OFF;
    float* out = (float*)d_out;

    hipMemsetAsync(am,    0,    (size_t)C*D*sizeof(float), stream);
    hipMemsetAsync(wcum,  0,    32*sizeof(int), stream);
    // slots + flag replicas + mist + req + respSlots all to -1
    hipMemsetAsync(slots, 0xFF,
        ((size_t)RWG*32 + 8*64 + 16 + (size_t)CWG*8)*sizeof(int), stream);

    build_am_kernel<<<dim3(10,32), 256, 0, stream>>>(am, X, labels);
    rownorm2_kernel<<<C, 256, 0, stream>>>(am, an);

    retrain_kernel<<<RWG, 256, 0, stream>>>(am, X, labels, Sfin, hv2,
                                            an, anf, wlist, wcum, slots, flagR, mist,
                                            req, rslot, grow);

    apply_out_kernel<<<10, 256, 0, stream>>>(am, X, wlist, wcum, mist, out);
    predict_kernel<<<N/4, 256, 0, stream>>>(out, X, anf, out + (size_t)C*D);
}

// Round 24
// 533.760 us; speedup vs baseline: 1.0850x; 1.0850x over previous
//
#include <hip/hip_runtime.h>

#define N 4096
#define D 10000
#define D4 2500          // D/4
#define C 10
#define NB 16            // number of 256-step blocks
#define B 256            // steps per block
#define CWG 1024         // corrector WGs (static 4-row ownership over all N)
#define ROWS 4           // rows per corrector WG
#define RWG (CWG + 1)    // retrain grid size
#define BAND 4           // rolling band (4 best: 6 cost +8us in R22)

// ---- workspace layout (float offsets) ----
#define AM_OFF    0                            // [C*D] (pad 100096) -- am0
#define SFIN_OFF  100096                       // [N*C] corrected scores
#define HV2_OFF   (SFIN_OFF + N*C)             // [N]
#define AN_OFF    (HV2_OFF + N)                // [16] initial ||am_c||^2
#define ANF_OFF   (AN_OFF + 16)                // [16] final   ||am_c||^2
#define WLIST_OFF (ANF_OFF + 16)               // [N] packed gidx|pred<<12|lab<<16
#define WCUM_OFF  (WLIST_OFF + N)              // [32] ints
#define SLOTS_OFF (WCUM_OFF + 32)              // [RWG*32] ints, phase-1 done slots
#define FLAG_OFF  (SLOTS_OFF + RWG*32)         // [8] int: (k+1)<<16 | Wtot (single line best)
#define MIST_OFF  (FLAG_OFF + 8)               // [8]
#define REQ_OFF   (MIST_OFF + 8)               // [8] int: (reqId<<12)|(k<<8)|jstar
#define RSLOT_OFF (REQ_OFF + 8)                // [CWG*8] ints: per-owner response slots
#define GROW_OFF  (RSLOT_OFF + CWG*8)          // [B] floats: on-demand G row

// ---------------- build_am: segment-sum, float4, register accumulate + atomics ------------
__global__ __launch_bounds__(256) void build_am_kernel(float* __restrict__ am,
        const float* __restrict__ X, const int* __restrict__ labels){
    int d4 = blockIdx.x*256 + threadIdx.x;
    if (d4 >= D4) return;
    int i0 = blockIdx.y * (N/32);
    const float4* X4 = (const float4*)X;
    float4 acc[C];
    #pragma unroll
    for (int c=0;c<C;c++) acc[c] = make_float4(0.f,0.f,0.f,0.f);
    for (int i=i0; i<i0+(N/32); ++i){
        int lab = labels[i];
        float4 x = X4[(size_t)i*D4 + d4];
        #pragma unroll
        for (int c=0;c<C;c++){
            float m = (lab==c) ? 1.f : 0.f;
            acc[c].x += m*x.x; acc[c].y += m*x.y; acc[c].z += m*x.z; acc[c].w += m*x.w;
        }
    }
    #pragma unroll
    for (int c=0;c<C;c++){
        float* p = &am[(size_t)c*D + d4*4];
        atomicAdd(p+0, acc[c].x); atomicAdd(p+1, acc[c].y);
        atomicAdd(p+2, acc[c].z); atomicAdd(p+3, acc[c].w);
    }
}

// ---------------- row sum-of-squares of am -> out[c] ----------------
__global__ __launch_bounds__(256) void rownorm2_kernel(const float* __restrict__ am,
        float* __restrict__ out){
    int c = blockIdx.x, t = threadIdx.x;
    const float4* a4 = (const float4*)(am + (size_t)c*D);
    float p = 0.f;
    for (int d=t; d<D4; d+=256){ float4 v = a4[d]; p += v.x*v.x+v.y*v.y+v.z*v.z+v.w*v.w; }
    #pragma unroll
    for (int off=32; off>=1; off>>=1) p += __shfl_down(p, off);
    __shared__ float wsum[4];
    int wid = t>>6, lane = t&63;
    if (lane==0) wsum[wid]=p;
    __syncthreads();
    if (t==0) out[c] = wsum[0]+wsum[1]+wsum[2]+wsum[3];
}

// ---- corrector chunk: 4 wrongs per d-pass ------------------------------------------------
#define CORR_PASS(wBeg, wEnd) \
    for (int w = (wBeg); w < (wEnd); w += 4){ \
        int n = (wEnd) - w; \
        int pk0 = wrongList[w]; \
        int pk1 = wrongList[(n>1)? w+1 : w]; \
        int pk2 = wrongList[(n>2)? w+2 : w]; \
        int pk3 = wrongList[(n>3)? w+3 : w]; \
        float e1=(n>1)?1.f:0.f, e2=(n>2)?1.f:0.f, e3=(n>3)?1.f:0.f; \
        const float4 *xw0 = X4+(size_t)(pk0&4095)*D4, *xw1 = X4+(size_t)(pk1&4095)*D4; \
        const float4 *xw2 = X4+(size_t)(pk2&4095)*D4, *xw3 = X4+(size_t)(pk3&4095)*D4; \
        float gg0[ROWS], gg1[ROWS], gg2[ROWS], gg3[ROWS]; \
        _Pragma("unroll") for (int r=0;r<ROWS;r++){ gg0[r]=0.f;gg1[r]=0.f;gg2[r]=0.f;gg3[r]=0.f; } \
        for (int d=t; d<D4; d+=256){ \
            float4 x0=xw0[d], x1=xw1[d], x2=xw2[d], x3=xw3[d]; \
            _Pragma("unroll") for (int r=0;r<ROWS;r++){ \
                float4 a = X4[(size_t)(R0+r)*D4 + d]; \
                gg0[r]+=a.x*x0.x+a.y*x0.y+a.z*x0.z+a.w*x0.w; \
                gg1[r]+=a.x*x1.x+a.y*x1.y+a.z*x1.z+a.w*x1.w; \
                gg2[r]+=a.x*x2.x+a.y*x2.y+a.z*x2.z+a.w*x2.w; \
                gg3[r]+=a.x*x3.x+a.y*x3.y+a.z*x3.z+a.w*x3.w; } \
        } \
        int p0=(pk0>>12)&15,l0=(pk0>>16)&15, p1=(pk1>>12)&15,l1=(pk1>>16)&15; \
        int p2=(pk2>>12)&15,l2=(pk2>>16)&15, p3=(pk3>>12)&15,l3=(pk3>>16)&15; \
        _Pragma("unroll") for (int c=0;c<C;c++){ \
            float c0 = ((c==l0)?1.f:0.f) - ((c==p0)?1.f:0.f); \
            float c1 = e1*(((c==l1)?1.f:0.f) - ((c==p1)?1.f:0.f)); \
            float c2 = e2*(((c==l2)?1.f:0.f) - ((c==p2)?1.f:0.f)); \
            float c3 = e3*(((c==l3)?1.f:0.f) - ((c==p3)?1.f:0.f)); \
            _Pragma("unroll") for (int r=0;r<ROWS;r++) \
                pp[r][c] += c0*gg0[r] + c1*gg1[r] + c2*gg2[r] + c3*gg3[r]; \
        } \
    }

// == retrain: WG0 = sequencer (on-demand G rows); WGs 1..1024 = correctors+row-servers =====
__global__ __launch_bounds__(256, 5) void retrain_kernel(
        const float* __restrict__ am, const float* __restrict__ X,
        const int* __restrict__ labels,
        float* __restrict__ Sfin, float* __restrict__ hv2g,
        const float* __restrict__ an0, float* __restrict__ anf,
        int* __restrict__ wrongList, int* __restrict__ Wcum,
        int* slots, int* flag, int* __restrict__ mist,
        int* req, int* respSlots, float* __restrict__ Grow){
    const int bx = blockIdx.x, t = threadIdx.x;
    const float4* X4 = (const float4*)X;
    __shared__ float red[ROWS][C+1][4];
    __shared__ float s0sm[ROWS][C];
    __shared__ int vvsm;

    if (bx == 0){
        // ---------------- sequencer ----------------
        float an[C], rstd[C];
        #pragma unroll
        for (int c=0;c<C;c++){ an[c]=an0[c]; rstd[c]=rsqrtf(an[c]); }
        int Wtot = 0;
        int reqId = 0;
        for (int k=0; k<NB; ++k){
            if (t < 64){
                while (__hip_atomic_load(&slots[(size_t)(1 + k*64 + t)*32],
                                         __ATOMIC_RELAXED, __HIP_MEMORY_SCOPE_AGENT) < 1)
                    __builtin_amdgcn_s_sleep(1);
            }
            __syncthreads();
            if (t==0) (void)__hip_atomic_load(&slots[32], __ATOMIC_ACQUIRE,
                                              __HIP_MEMORY_SCOPE_AGENT);
            __syncthreads();

            if (t < 64){
                const int lane = t;
                const int base = k*B;
                float s[4][C];
                float h2o[4]; int labo[4];
                #pragma unroll
                for (int q=0;q<4;q++){
                    int j = q*64 + lane;
                    #pragma unroll
                    for (int c=0;c<C;c++) s[q][c] = Sfin[(size_t)(base+j)*C + c];
                    h2o[q] = hv2g[base + j];
                    labo[q] = labels[base + j];
                }
                int pos = -1;
                while (true){
                    int pred[4];
                    #pragma unroll
                    for (int q=0;q<4;q++){
                        float best = s[q][0]*rstd[0]; int bi=0;
                        #pragma unroll
                        for (int c=1;c<C;c++){
                            float v = s[q][c]*rstd[c];
                            if (v>best){best=v;bi=c;}
                        }
                        pred[q]=bi;
                    }
                    int jstar = 256;
                    #pragma unroll
                    for (int q=0;q<4;q++){
                        unsigned long long m =
                            __ballot((pred[q]!=labo[q]) && (q*64+lane > pos));
                        if (jstar==256 && m!=0ull)
                            jstar = q*64 + (__ffsll((unsigned long long)m)-1);
                    }
                    if (jstar >= 256) break;
                    // publish on-demand G-row request EARLY (owners compute while we update)
                    int reqWord = (reqId<<12) | (k<<8) | jstar;
                    if (lane==0)
                        __hip_atomic_store(req, reqWord, __ATOMIC_RELEASE,
                                           __HIP_MEMORY_SCOPE_AGENT);
                    reqId++;
                    int qs = jstar>>6, ls = jstar&63;
                    float sqs[C];
                    #pragma unroll
                    for (int c=0;c<C;c++)
                        sqs[c] = (qs==0)? s[0][c] : (qs==1)? s[1][c]
                               : (qs==2)? s[2][c] : s[3][c];
                    int predqs = (qs==0)? pred[0] : (qs==1)? pred[1]
                               : (qs==2)? pred[2] : pred[3];
                    int labqs  = (qs==0)? labo[0] : (qs==1)? labo[1]
                               : (qs==2)? labo[2] : labo[3];
                    float h2qs = (qs==0)? h2o[0] : (qs==1)? h2o[1]
                               : (qs==2)? h2o[2] : h2o[3];
                    float brawme = sqs[0], slvme = sqs[0];
                    #pragma unroll
                    for (int c=1;c<C;c++){
                        brawme = (c==predqs)? sqs[c] : brawme;
                        slvme  = (c==labqs)?  sqs[c] : slvme;
                    }
                    float brawB = __shfl(brawme, ls);
                    float slvB  = __shfl(slvme,  ls);
                    float h2b   = __shfl(h2qs,   ls);
                    int   pkB   = __shfl(predqs | (labqs<<8), ls);
                    int biB = pkB & 255, labB = (pkB>>8) & 255;
                    if (lane==0)
                        wrongList[Wtot] = (base + jstar) | (biB<<12) | (labB<<16);
                    Wtot++;
                    float anp = an[0], anl = an[0];
                    #pragma unroll
                    for (int c=1;c<C;c++){ anp=(c==biB)?an[c]:anp; anl=(c==labB)?an[c]:anl; }
                    float anp_new = anp - 2.f*brawB + h2b;
                    float anl_new = anl + 2.f*slvB  + h2b;
                    float rp = rsqrtf(anp_new), rl = rsqrtf(anl_new);
                    #pragma unroll
                    for (int c=0;c<C;c++){
                        an[c]   = (c==biB)? anp_new : (c==labB)? anl_new : an[c];
                        rstd[c] = (c==biB)? rp      : (c==labB)? rl      : rstd[c];
                    }
                    // wait for all 64 owner responses (per-owner slots, no RMW)
                    while (__hip_atomic_load(&respSlots[(size_t)(k*64+lane)*8],
                               __ATOMIC_RELAXED, __HIP_MEMORY_SCOPE_AGENT) != reqWord){}
                    (void)__hip_atomic_load(&respSlots[(size_t)(k*64+lane)*8],
                               __ATOMIC_ACQUIRE, __HIP_MEMORY_SCOPE_AGENT);
                    float grow[4];
                    #pragma unroll
                    for (int sl=0;sl<4;sl++) grow[sl] = Grow[sl*64 + lane];
                    #pragma unroll
                    for (int c=0;c<C;c++){
                        float sg = (c==biB)? -1.f : (c==labB)? 1.f : 0.f;
                        #pragma unroll
                        for (int sl=0;sl<4;sl++) s[sl][c] += sg * grow[sl];
                    }
                    pos = jstar;
                }
            }
            __syncthreads();
            if (t==0){
                Wcum[k+1] = Wtot;
                __hip_atomic_store(flag, ((k+1)<<16) | Wtot,
                                   __ATOMIC_RELEASE, __HIP_MEMORY_SCOPE_AGENT);
            }
        }
        if (t==0){
            mist[0] = Wtot;
            #pragma unroll
            for (int c=0;c<C;c++) anf[c] = an[c];
        }
    } else {
        // ---- corrector: rows R0..R0+3 of block m; band + s0 prologue + events + service --
        const int R0 = 4*(bx-1);
        const int m  = (bx-1) >> 6;
        if (m > BAND){
            if (t==0){
                while ((__hip_atomic_load(flag, __ATOMIC_RELAXED,
                            __HIP_MEMORY_SCOPE_AGENT) >> 16) < m - BAND)
                    __builtin_amdgcn_s_sleep(8);
            }
            __syncthreads();
        }
        {   // prologue: S0 (own 4 rows vs am0) + hv2
            const float4* a4 = (const float4*)am;
            float p0[ROWS][C]; float px[ROWS];
            #pragma unroll
            for (int r=0;r<ROWS;r++){ px[r]=0.f;
                #pragma unroll
                for (int c=0;c<C;c++) p0[r][c]=0.f; }
            for (int d=t; d<D4; d+=256){
                float4 x0 = X4[(size_t)(R0+0)*D4 + d];
                float4 x1 = X4[(size_t)(R0+1)*D4 + d];
                float4 x2 = X4[(size_t)(R0+2)*D4 + d];
                float4 x3 = X4[(size_t)(R0+3)*D4 + d];
                px[0] += x0.x*x0.x + x0.y*x0.y + x0.z*x0.z + x0.w*x0.w;
                px[1] += x1.x*x1.x + x1.y*x1.y + x1.z*x1.z + x1.w*x1.w;
                px[2] += x2.x*x2.x + x2.y*x2.y + x2.z*x2.z + x2.w*x2.w;
                px[3] += x3.x*x3.x + x3.y*x3.y + x3.z*x3.z + x3.w*x3.w;
                #pragma unroll
                for (int c=0;c<C;c++){
                    float4 a = a4[(size_t)c*D4 + d];
                    p0[0][c] += x0.x*a.x + x0.y*a.y + x0.z*a.z + x0.w*a.w;
                    p0[1][c] += x1.x*a.x + x1.y*a.y + x1.z*a.z + x1.w*a.w;
                    p0[2][c] += x2.x*a.x + x2.y*a.y + x2.z*a.z + x2.w*a.w;
                    p0[3][c] += x3.x*a.x + x3.y*a.y + x3.z*a.z + x3.w*a.w;
                }
            }
            int wid=t>>6, lane=t&63;
            #pragma unroll
            for (int r=0;r<ROWS;r++){
                #pragma unroll
                for (int v=0; v<C+1; ++v){
                    float xv = (v<C)? p0[r][v] : px[r];
                    #pragma unroll
                    for (int off=32; off>=1; off>>=1) xv += __shfl_down(xv, off);
                    if (lane==0) red[r][v][wid] = xv;
                }
            }
            __syncthreads();
            if (t < ROWS*(C+1)){
                int r = t/(C+1), v = t%(C+1);
                float s = red[r][v][0]+red[r][v][1]+red[r][v][2]+red[r][v][3];
                if (v < C) s0sm[r][v] = s;
                else hv2g[R0 + r] = s;
            }
            __syncthreads();
        }
        float pp[ROWS][C];
        #pragma unroll
        for (int r=0;r<ROWS;r++)
            #pragma unroll
            for (int c=0;c<C;c++) pp[r][c]=0.f;

        int W0 = 0;
        for (int v = 1; v <= m; ){
            if (t==0){
                int f;
                while (((f = __hip_atomic_load(flag, __ATOMIC_RELAXED,
                                 __HIP_MEMORY_SCOPE_AGENT)) >> 16) < v)
                    __builtin_amdgcn_s_sleep(1);
                (void)__hip_atomic_load(flag, __ATOMIC_ACQUIRE, __HIP_MEMORY_SCOPE_AGENT);
                int fv = f >> 16;
                vvsm = (fv < m) ? fv : m;
            }
            __syncthreads();
            int vv = vvsm;
            int end = Wcum[vv];
            CORR_PASS(W0, end)
            W0 = end;
            v = vv + 1;
            __syncthreads();
        }
        if (W0 == 0){
            if (t < ROWS*C){
                int r = t / C, c = t % C;
                Sfin[(size_t)(R0 + r)*C + c] = s0sm[r][c];
            }
            __syncthreads();
        } else {
            int wid=t>>6, lane=t&63;
            #pragma unroll
            for (int r=0;r<ROWS;r++)
                #pragma unroll
                for (int c=0;c<C;c++){
                    float xv = pp[r][c];
                    #pragma unroll
                    for (int off=32; off>=1; off>>=1) xv += __shfl_down(xv, off);
                    if (lane==0) red[r][c][wid] = xv;
                }
            __syncthreads();
            if (t < ROWS*C){
                int r = t / C, c = t % C;
                float vsum = red[r][c][0]+red[r][c][1]+red[r][c][2]+red[r][c][3];
                Sfin[(size_t)(R0 + r)*C + c] = s0sm[r][c] + vsum;
            }
            __syncthreads();
        }
        if (t==0) __hip_atomic_store(&slots[(size_t)bx*32], 1, __ATOMIC_RELEASE,
                                     __HIP_MEMORY_SCOPE_AGENT);

        // ---- service loop: compute on-demand G rows for own block m until seq passes it --
        int lastReq = -1;
        while (true){
            if (t==0){
                int r;
                while (true){
                    int f = __hip_atomic_load(flag, __ATOMIC_RELAXED,
                                              __HIP_MEMORY_SCOPE_AGENT) >> 16;
                    if (f >= m+1){ r = -1; break; }
                    r = __hip_atomic_load(req, __ATOMIC_RELAXED, __HIP_MEMORY_SCOPE_AGENT);
                    if (r >= 0 && r != lastReq && (((r>>8)&15) == m)){
                        (void)__hip_atomic_load(req, __ATOMIC_ACQUIRE,
                                                __HIP_MEMORY_SCOPE_AGENT);
                        break;
                    }
                    __builtin_amdgcn_s_sleep(1);
                }
                vvsm = r;
            }
            __syncthreads();
            int r = vvsm;
            if (r < 0) break;
            lastReq = r;
            {
                int jstar = r & 255;
                const float4* xw = X4 + (size_t)(m*B + jstar)*D4;
                float g0=0.f,g1=0.f,g2=0.f,g3=0.f;
                for (int d=t; d<D4; d+=256){
                    float4 v = xw[d];
                    float4 a0 = X4[(size_t)(R0+0)*D4 + d];
                    float4 a1 = X4[(size_t)(R0+1)*D4 + d];
                    float4 a2 = X4[(size_t)(R0+2)*D4 + d];
                    float4 a3 = X4[(size_t)(R0+3)*D4 + d];
                    g0 += a0.x*v.x + a0.y*v.y + a0.z*v.z + a0.w*v.w;
                    g1 += a1.x*v.x + a1.y*v.y + a1.z*v.z + a1.w*v.w;
                    g2 += a2.x*v.x + a2.y*v.y + a2.z*v.z + a2.w*v.w;
                    g3 += a3.x*v.x + a3.y*v.y + a3.z*v.z + a3.w*v.w;
                }
                int wid=t>>6, lane=t&63;
                #pragma unroll
                for (int off=32; off>=1; off>>=1){
                    g0 += __shfl_down(g0, off); g1 += __shfl_down(g1, off);
                    g2 += __shfl_down(g2, off); g3 += __shfl_down(g3, off);
                }
                if (lane==0){
                    red[0][0][wid]=g0; red[1][0][wid]=g1;
                    red[2][0][wid]=g2; red[3][0][wid]=g3;
                }
                __syncthreads();
                if (t < 4){
                    float s = red[t][0][0]+red[t][0][1]+red[t][0][2]+red[t][0][3];
                    Grow[(R0 - m*B) + t] = s;
                }
                __syncthreads();
                if (t==0)
                    __hip_atomic_store(&respSlots[(size_t)(bx-1)*8], r,
                                       __ATOMIC_RELEASE, __HIP_MEMORY_SCOPE_AGENT);
                __syncthreads();
            }
        }
    }
}

// ---- apply all wrongs to am0, write am_final + mistakes DIRECTLY to out -----------------
__global__ __launch_bounds__(256) void apply_out_kernel(const float* __restrict__ am,
        const float* __restrict__ X, const int* __restrict__ wrongList,
        const int* __restrict__ Wcum, const int* __restrict__ mist, float* __restrict__ out){
    int d4 = blockIdx.x*256 + threadIdx.x;
    if (blockIdx.x==0 && threadIdx.x==0) out[(size_t)C*D + N] = (float)mist[0];
    if (d4 >= D4) return;
    int W = Wcum[NB];
    const float4* X4 = (const float4*)X;
    float4 acc[C];
    #pragma unroll
    for (int c=0;c<C;c++) acc[c] = make_float4(0.f,0.f,0.f,0.f);
    for (int w=0; w<W; ++w){
        int pk = wrongList[w];
        int gw = pk & 4095, pcl=(pk>>12)&15, lcl=(pk>>16)&15;
        float4 x = X4[(size_t)gw*D4 + d4];
        #pragma unroll
        for (int c=0;c<C;c++){
            float coef = ((c==lcl)?1.f:0.f) - ((c==pcl)?1.f:0.f);
            acc[c].x += coef*x.x; acc[c].y += coef*x.y;
            acc[c].z += coef*x.z; acc[c].w += coef*x.w;
        }
    }
    const float4* am4 = (const float4*)am;
    float4* out4 = (float4*)out;
    #pragma unroll
    for (int c=0;c<C;c++){                      // write ALL elements (out is poisoned)
        float4 v = am4[(size_t)c*D4 + d4];
        v.x += acc[c].x; v.y += acc[c].y; v.z += acc[c].z; v.w += acc[c].w;
        out4[(size_t)c*D4 + d4] = v;
    }
}

// ---------------- final predict: 4 rows/WG, float4 (reads am_final from out) --------------
__global__ __launch_bounds__(256) void predict_kernel(const float* __restrict__ am,
        const float* __restrict__ X, const float* __restrict__ anf, float* __restrict__ outPred){
    int i0 = blockIdx.x*4, t = threadIdx.x;
    const float4* a4 = (const float4*)am;
    const float4* X4 = (const float4*)X;
    float p[4][C];
    #pragma unroll
    for (int r=0;r<4;r++)
        #pragma unroll
        for (int c=0;c<C;c++) p[r][c]=0.f;
    for (int d=t; d<D4; d+=256){
        float4 x0 = X4[(size_t)(i0+0)*D4 + d];
        float4 x1 = X4[(size_t)(i0+1)*D4 + d];
        float4 x2 = X4[(size_t)(i0+2)*D4 + d];
        float4 x3 = X4[(size_t)(i0+3)*D4 + d];
        #pragma unroll
        for (int c=0;c<C;c++){
            float4 a = a4[(size_t)c*D4 + d];
            p[0][c] += x0.x*a.x + x0.y*a.y + x0.z*a.z + x0.w*a.w;
            p[1][c] += x1.x*a.x + x1.y*a.y + x1.z*a.z + x1.w*a.w;
            p[2][c] += x2.x*a.x + x2.y*a.y + x2.z*a.z + x2.w*a.w;
            p[3][c] += x3.x*a.x + x3.y*a.y + x3.z*a.z + x3.w*a.w;
        }
    }
    __shared__ float red[4][C][4];
    int wid=t>>6, lane=t&63;
    #pragma unroll
    for (int r=0;r<4;r++)
        #pragma unroll
        for (int c=0;c<C;c++){
            float x = p[r][c];
            #pragma unroll
            for (int off=32; off>=1; off>>=1) x += __shfl_down(x, off);
            if (lane==0) red[r][c][wid] = x;
        }
    __syncthreads();
    if (t < 4){
        float best = -3.4e38f; int bi = 0;
        #pragma unroll
        for (int c=0;c<C;c++){
            float dot = red[t][c][0]+red[t][c][1]+red[t][c][2]+red[t][c][3];
            float v = dot * rsqrtf(anf[c]);
            if (v > best){ best = v; bi = c; }
        }
        outPred[i0 + t] = (float)bi;
    }
}

extern "C" void kernel_launch(void* const* d_in, const int* in_sizes, int n_in,
                              void* d_out, int out_size, void* d_ws, size_t ws_size,
                              hipStream_t stream){
    const float* X      = (const float*)d_in[0];
    const int*   labels = (const int*)d_in[1];
    float* ws   = (float*)d_ws;
    float* am   = ws + AM_OFF;
    float* Sfin = ws + SFIN_OFF;
    float* hv2  = ws + HV2_OFF;
    float* an   = ws + AN_OFF;
    float* anf  = ws + ANF_OFF;
    int*   wlist = (int*)(ws + WLIST_OFF);
    int*   wcum  = (int*)(ws + WCUM_OFF);
    int*   slots = (int*)(ws + SLOTS_OFF);
    int*   flag  = (int*)(ws + FLAG_OFF);
    int*   mist  = (int*)(ws + MIST_OFF);
    int*   req   = (int*)(ws + REQ_OFF);
    int*   rslot = (int*)(ws + RSLOT_OFF);
    float* grow  = ws + GROW_OFF;
    float* out = (float*)d_out;

    hipMemsetAsync(am,    0,    (size_t)C*D*sizeof(float), stream);
    hipMemsetAsync(wcum,  0,    32*sizeof(int), stream);
    // slots + flag + mist + req + respSlots all to -1
    hipMemsetAsync(slots, 0xFF, ((size_t)RWG*32 + 24 + (size_t)CWG*8)*sizeof(int), stream);

    build_am_kernel<<<dim3(10,32), 256, 0, stream>>>(am, X, labels);
    rownorm2_kernel<<<C, 256, 0, stream>>>(am, an);

    retrain_kernel<<<RWG, 256, 0, stream>>>(am, X, labels, Sfin, hv2,
                                            an, anf, wlist, wcum, slots, flag, mist,
                                            req, rslot, grow);

    apply_out_kernel<<<10, 256, 0, stream>>>(am, X, wlist, wcum, mist, out);
    predict_kernel<<<N/4, 256, 0, stream>>>(out, X, anf, out + (size_t)C*D);
}